// Round 6
// baseline (586.311 us; speedup 1.0000x reference)
//
#include <hip/hip_runtime.h>
#include <cstdint>
#include <cstddef>

#define L 8192
#define BATCH 4
#define DQK 512
#define M_TOT (BATCH*L)   // 32768 positions
#define NSEG 128          // segments per batch
#define SEGC 64           // chunks per segment
#define EPSC 1e-8f

typedef __attribute__((ext_vector_type(8))) short bf16x8;
typedef __attribute__((ext_vector_type(4))) float f32x4;
typedef __attribute__((ext_vector_type(8))) unsigned short u16x8;

// ---------- helpers ----------
__device__ __forceinline__ unsigned short bf16_rne(float x) {
  union { float f; unsigned u; } v; v.f = x;
  unsigned r = v.u + 0x7fffu + ((v.u >> 16) & 1u);
  return (unsigned short)(r >> 16);
}
__device__ __forceinline__ float bf16_tof(unsigned short b) {
  union { unsigned u; float f; } v; v.u = ((unsigned)b) << 16;
  return v.f;
}
__device__ __forceinline__ void gload_lds16(const void* g, void* l) {
  __builtin_amdgcn_global_load_lds(
      (const __attribute__((address_space(1))) unsigned int*)g,
      (__attribute__((address_space(3))) unsigned int*)l, 16, 0, 0);
}

// ---------------- K0: split f32 -> 3x bf16 ----------------
__global__ __launch_bounds__(256) void k_split(const float* __restrict__ tokens,
                                               const float* __restrict__ Wqk,
                                               unsigned short* __restrict__ A1,
                                               unsigned short* __restrict__ A2,
                                               unsigned short* __restrict__ A3,
                                               unsigned short* __restrict__ W1,
                                               unsigned short* __restrict__ W2,
                                               unsigned short* __restrict__ W3) {
  const float* src; unsigned short *d1, *d2, *d3; size_t e0;
  if (blockIdx.x < 8192) {
    src = tokens; d1 = A1; d2 = A2; d3 = A3;
    e0 = ((size_t)blockIdx.x * 256 + threadIdx.x) * 8;
  } else {
    src = Wqk; d1 = W1; d2 = W2; d3 = W3;
    e0 = ((size_t)(blockIdx.x - 8192) * 256 + threadIdx.x) * 8;
  }
  float v[8];
  *(float4*)&v[0] = *(const float4*)(src + e0);
  *(float4*)&v[4] = *(const float4*)(src + e0 + 4);
  unsigned short o1[8], o2[8], o3[8];
  #pragma unroll
  for (int j = 0; j < 8; ++j) {
    float x = v[j];
    unsigned short b1 = bf16_rne(x);
    float r1 = x - bf16_tof(b1);
    unsigned short b2 = bf16_rne(r1);
    float r2 = r1 - bf16_tof(b2);
    unsigned short b3 = bf16_rne(r2);
    o1[j] = b1; o2[j] = b2; o3[j] = b3;
  }
  *(u16x8*)(d1 + e0) = *(u16x8*)o1;
  *(u16x8*)(d2 + e0) = *(u16x8*)o2;
  *(u16x8*)(d3 + e0) = *(u16x8*)o3;
}

// ---------------- K0b: zero dot/nq/nk accumulators ----------------
__global__ __launch_bounds__(256) void k_zero3(float* __restrict__ buf) {
  buf[blockIdx.x * 256 + threadIdx.x] = 0.f;   // grid sized exactly
}

// -------- K1f: fused bf16x3 MFMA GEMM (128x256 merged q|k tile) + cos partials --------
// grid 1024: 256 row-tiles x 4 col-groups. 8 waves: wr=w>>2 row-half, wq=w&3
// (wq<2 -> q-cols cg*128+wq*64.., wq>=2 -> k-cols 512+cg*128+(wq-2)*64..).
// Epilogue computes dot[p]=sum q[p,c]*k[p-1,c+512], nq[p], nk[row] via LDS pairing
// + atomics; straddle row p=r0 handled by qstr/kstr + k_straddle. qk NEVER written.
__global__ __launch_bounds__(512, 4) void k_gemm_fused(
    const unsigned short* __restrict__ A1, const unsigned short* __restrict__ A2,
    const unsigned short* __restrict__ A3,
    const unsigned short* __restrict__ W1, const unsigned short* __restrict__ W2,
    const unsigned short* __restrict__ W3,
    float* __restrict__ dotv, float* __restrict__ nqrow, float* __restrict__ nkrow,
    float* __restrict__ qstr, float* __restrict__ kstr) {
  __shared__ unsigned short lds[9 * 512 * 8];   // 72 KB staging; reused as kbuf
  // XCD-chunked swizzle: 1024 blocks, 128/XCD; cg fastest -> 4 blocks/A-panel per L2
  const int g = (blockIdx.x & 7) * 128 + (blockIdx.x >> 3);
  const int cg = g & 3;     // col group (128 q-cols + matching 128 k-cols)
  const int by = g >> 2;    // row tile (32768/128)
  const int t = threadIdx.x;
  const int lane = t & 63;
  const int w = t >> 6;
  const int wr = w >> 2;        // 0..1
  const int wq = w & 3;         // 0..3
  const int kg = lane >> 4;
  const int fr = lane & 15;
  const int fq = lane >> 4;     // same as kg; epilogue alias

  f32x4 acc[4][4];
  #pragma unroll
  for (int i = 0; i < 4; ++i)
    #pragma unroll
    for (int j = 0; j < 4; ++j) acc[i][j] = (f32x4){0.f, 0.f, 0.f, 0.f};

  const unsigned short* srcA[3] = {A1, A2, A3};
  const unsigned short* srcW[3] = {W1, W2, W3};
  const int arow = by * 128;
  const int btile = 3 + ((wq >= 2) ? 3 : 0);        // BQ tiles 3..5, BK tiles 6..8
  const int colbase = (wq & 1) * 64;

  const int ldrow = t & 127, ldkg = t >> 7;
  for (int ks = 0; ks < 16; ++ks) {
    __syncthreads();
    const int kofs = ks * 32 + ldkg * 8;
    #pragma unroll
    for (int s = 0; s < 3; ++s) {
      gload_lds16(srcA[s] + (size_t)(arow + ldrow) * 512 + kofs,
                  &lds[((s) * 512 + t) * 8]);
      gload_lds16(srcW[s] + (size_t)(cg * 128 + ldrow) * 512 + kofs,
                  &lds[((3 + s) * 512 + t) * 8]);
      gload_lds16(srcW[s] + (size_t)(512 + cg * 128 + ldrow) * 512 + kofs,
                  &lds[((6 + s) * 512 + t) * 8]);
    }
    __syncthreads();

    bf16x8 bfr[4][3];
    #pragma unroll
    for (int nf = 0; nf < 4; ++nf) {
      const int row = colbase + nf * 16 + fr;
      #pragma unroll
      for (int s = 0; s < 3; ++s)
        bfr[nf][s] = *(const bf16x8*)&lds[(((btile + s) * 512) + kg * 128 + row) * 8];
    }
    #pragma unroll
    for (int mf = 0; mf < 4; ++mf) {
      const int row = wr * 64 + mf * 16 + fr;
      bf16x8 a1 = *(const bf16x8*)&lds[((0 * 512) + kg * 128 + row) * 8];
      bf16x8 a2 = *(const bf16x8*)&lds[((1 * 512) + kg * 128 + row) * 8];
      bf16x8 a3 = *(const bf16x8*)&lds[((2 * 512) + kg * 128 + row) * 8];
      #pragma unroll
      for (int nf = 0; nf < 4; ++nf) {
        f32x4 c = acc[mf][nf];
        c = __builtin_amdgcn_mfma_f32_16x16x32_bf16(a1, bfr[nf][0], c, 0, 0, 0);
        c = __builtin_amdgcn_mfma_f32_16x16x32_bf16(a1, bfr[nf][1], c, 0, 0, 0);
        c = __builtin_amdgcn_mfma_f32_16x16x32_bf16(a2, bfr[nf][0], c, 0, 0, 0);
        c = __builtin_amdgcn_mfma_f32_16x16x32_bf16(a2, bfr[nf][1], c, 0, 0, 0);
        c = __builtin_amdgcn_mfma_f32_16x16x32_bf16(a1, bfr[nf][2], c, 0, 0, 0);
        c = __builtin_amdgcn_mfma_f32_16x16x32_bf16(a3, bfr[nf][0], c, 0, 0, 0);
        acc[mf][nf] = c;
      }
    }
  }

  // ---- epilogue: in-block cos partials ----
  float* kbuf = (float*)lds;      // [128][132] f32 = 67.6 KB
  __syncthreads();                // k-loop LDS reads done
  if (wq >= 2) {                  // k-waves dump C to LDS
    #pragma unroll
    for (int mf = 0; mf < 4; ++mf)
      #pragma unroll
      for (int nf = 0; nf < 4; ++nf)
        #pragma unroll
        for (int r = 0; r < 4; ++r)
          kbuf[(wr*64 + mf*16 + fq*4 + r) * 132 + colbase + nf*16 + fr] = acc[mf][nf][r];
  }
  __syncthreads();

  if (wq < 2) {                   // q-waves: pair with k[p-1], reduce, atomics
    #pragma unroll
    for (int mf = 0; mf < 4; ++mf) {
      #pragma unroll
      for (int r = 0; r < 4; ++r) {
        const int row = wr*64 + mf*16 + fq*4 + r;
        float v = 0.f, nqv = 0.f;
        #pragma unroll
        for (int nf = 0; nf < 4; ++nf) {
          const float qv = acc[mf][nf][r];
          nqv = fmaf(qv, qv, nqv);
          if (row > 0)
            v = fmaf(qv, kbuf[(row-1)*132 + colbase + nf*16 + fr], v);
        }
        #pragma unroll
        for (int m = 1; m < 16; m <<= 1) {
          v   += __shfl_xor(v, m);
          nqv += __shfl_xor(nqv, m);
        }
        if (fr == 0) {
          const int gp = by*128 + row;
          atomicAdd(&nqrow[gp], nqv);
          if (row > 0) atomicAdd(&dotv[gp], v);
        }
      }
    }
    if (wr == 0 && fq == 0) {     // straddle q-row r0
      #pragma unroll
      for (int nf = 0; nf < 4; ++nf)
        qstr[(size_t)by*512 + cg*128 + colbase + nf*16 + fr] = acc[0][nf][0];
    }
  } else {                        // k-waves: norms + straddle k-row r0+127
    #pragma unroll
    for (int mf = 0; mf < 4; ++mf) {
      #pragma unroll
      for (int r = 0; r < 4; ++r) {
        const int row = wr*64 + mf*16 + fq*4 + r;
        float nkv = 0.f;
        #pragma unroll
        for (int nf = 0; nf < 4; ++nf) {
          const float kv = acc[mf][nf][r];
          nkv = fmaf(kv, kv, nkv);
        }
        #pragma unroll
        for (int m = 1; m < 16; m <<= 1) nkv += __shfl_xor(nkv, m);
        if (fr == 0) atomicAdd(&nkrow[by*128 + row], nkv);
      }
    }
    if (wr == 1 && fq == 3) {
      #pragma unroll
      for (int nf = 0; nf < 4; ++nf)
        kstr[(size_t)by*512 + cg*128 + colbase + nf*16 + fr] = acc[3][nf][3];
    }
  }
}

// ---------------- K1s: straddle dots (one wave per row-tile) ----------------
__global__ __launch_bounds__(256) void k_straddle(const float* __restrict__ qstr,
                                                  const float* __restrict__ kstr,
                                                  const float* __restrict__ skey,
                                                  const float* __restrict__ nkrow,
                                                  float* __restrict__ dotv,
                                                  float* __restrict__ nkS) {
  const int tile = blockIdx.x * 4 + (threadIdx.x >> 6);   // 0..255
  const int lane = threadIdx.x & 63;
  const int p = tile * 128;
  const bool isStart = ((tile & 63) == 0);                // n == 0
  const float* q  = qstr + (size_t)tile * 512;
  const float* pk = isStart ? skey : (kstr + (size_t)(tile - 1) * 512);
  float v = 0.f, u = 0.f;
  const int e0 = lane * 8;
  #pragma unroll
  for (int j = 0; j < 8; j += 4) {
    float4 qv = *(const float4*)(q + e0 + j);
    float4 kv = *(const float4*)(pk + e0 + j);
    v = fmaf(qv.x,kv.x,v); v = fmaf(qv.y,kv.y,v);
    v = fmaf(qv.z,kv.z,v); v = fmaf(qv.w,kv.w,v);
    u = fmaf(kv.x,kv.x,u); u = fmaf(kv.y,kv.y,u);
    u = fmaf(kv.z,kv.z,u); u = fmaf(kv.w,kv.w,u);
  }
  #pragma unroll
  for (int m = 32; m >= 1; m >>= 1) { v += __shfl_xor(v,m); u += __shfl_xor(u,m); }
  if (lane == 0) {
    dotv[p] = v;
    nkS[tile] = isStart ? u : nkrow[p - 1];
  }
}

// ---------------- K2f: finalize probs from accumulators ----------------
__global__ __launch_bounds__(256) void k_probs(const float* __restrict__ dotv,
                                               const float* __restrict__ nqrow,
                                               const float* __restrict__ nkrow,
                                               const float* __restrict__ nkS,
                                               float* __restrict__ probs) {
  const int i = blockIdx.x * 256 + threadIdx.x;
  const float nq = nqrow[i];
  const float nk = ((i & 127) == 0) ? nkS[i >> 7] : nkrow[i - 1];
  const float c = dotv[i] / (fmaxf(sqrtf(nq), EPSC) * fmaxf(sqrtf(nk), EPSC));
  probs[i] = 0.5f * (1.f - c);
}

// ---------------- K1: fallback f32 GEMM ----------------
__global__ __launch_bounds__(256) void k_gemm(const float* __restrict__ A,
                                              const float* __restrict__ W,
                                              float* __restrict__ C) {
  __shared__ float As[8][128];
  __shared__ float Bs[8][128];
  const int bx = blockIdx.x & 7;
  const int by = blockIdx.x >> 3;
  const int t  = threadIdx.x;
  const int tx = t & 15, ty = t >> 4;
  const int lr = t >> 1;
  const int lc = (t & 1) * 4;
  const float* Ag = A + (size_t)(by*128 + lr)*512 + lc;
  const float* Wg = W + (size_t)(bx*128 + lr)*512 + lc;
  float acc[8][8];
  #pragma unroll
  for (int i=0;i<8;i++)
    #pragma unroll
    for (int j=0;j<8;j++) acc[i][j]=0.f;

  for (int k0 = 0; k0 < 512; k0 += 8) {
    float4 av = *(const float4*)(Ag + k0);
    float4 bv = *(const float4*)(Wg + k0);
    __syncthreads();
    As[lc+0][lr]=av.x; As[lc+1][lr]=av.y; As[lc+2][lr]=av.z; As[lc+3][lr]=av.w;
    Bs[lc+0][lr]=bv.x; Bs[lc+1][lr]=bv.y; Bs[lc+2][lr]=bv.z; Bs[lc+3][lr]=bv.w;
    __syncthreads();
    #pragma unroll
    for (int kk=0;kk<8;kk++) {
      float af[8], bf[8];
      *(float4*)&af[0] = *(const float4*)&As[kk][ty*8];
      *(float4*)&af[4] = *(const float4*)&As[kk][ty*8+4];
      *(float4*)&bf[0] = *(const float4*)&Bs[kk][tx*8];
      *(float4*)&bf[4] = *(const float4*)&Bs[kk][tx*8+4];
      #pragma unroll
      for (int i=0;i<8;i++)
        #pragma unroll
        for (int j=0;j<8;j++)
          acc[i][j] = fmaf(af[i], bf[j], acc[i][j]);
    }
  }
  const int crow = by*128 + ty*8;
  const int ccol = bx*128 + tx*8;
  #pragma unroll
  for (int i=0;i<8;i++) {
    float* cp = C + (size_t)(crow+i)*1024 + ccol;
    *(float4*)cp     = make_float4(acc[i][0],acc[i][1],acc[i][2],acc[i][3]);
    *(float4*)(cp+4) = make_float4(acc[i][4],acc[i][5],acc[i][6],acc[i][7]);
  }
}

// ---------------- K2: fallback cosine -> probs ----------------
__global__ __launch_bounds__(256) void k_cos(const float* __restrict__ qk,
                                             const float* __restrict__ start_key,
                                             float* __restrict__ probs) {
  const int wid = threadIdx.x >> 6;
  const int lane = threadIdx.x & 63;
  const int p = blockIdx.x*4 + wid;
  const int n = p & (L-1);
  const float* q  = qk + (size_t)p*1024;
  const float* ks = (n==0) ? start_key : (qk + (size_t)(p-1)*1024 + 512);
  float dot=0.f, nq=0.f, nk=0.f;
  const int e0 = lane*8;
  #pragma unroll
  for (int j=0;j<8;j+=4) {
    float4 qv = *(const float4*)(q+e0+j);
    float4 kv = *(const float4*)(ks+e0+j);
    dot = fmaf(qv.x,kv.x,dot); dot = fmaf(qv.y,kv.y,dot);
    dot = fmaf(qv.z,kv.z,dot); dot = fmaf(qv.w,kv.w,dot);
    nq  = fmaf(qv.x,qv.x,nq);  nq  = fmaf(qv.y,qv.y,nq);
    nq  = fmaf(qv.z,qv.z,nq);  nq  = fmaf(qv.w,qv.w,nq);
    nk  = fmaf(kv.x,kv.x,nk);  nk  = fmaf(kv.y,kv.y,nk);
    nk  = fmaf(kv.z,kv.z,nk);  nk  = fmaf(kv.w,kv.w,nk);
  }
  #pragma unroll
  for (int m=32;m>=1;m>>=1) {
    dot += __shfl_xor(dot,m);
    nq  += __shfl_xor(nq,m);
    nk  += __shfl_xor(nk,m);
  }
  if (lane==0) {
    float na = fmaxf(sqrtf(nq), EPSC);
    float nb = fmaxf(sqrtf(nk), EPSC);
    float c  = dot/(na*nb);
    probs[p] = 0.5f*(1.f - c);
  }
}

// ---------------- K3: per-batch boundary prefix-scan, bpos, aux ----------------
__global__ __launch_bounds__(1024) void k_scan_bd(const float* __restrict__ probs,
                                                  int* __restrict__ bpos,
                                                  int* __restrict__ num_chunks,
                                                  float* __restrict__ auxvals) {
  const int b = blockIdx.x;
  const float* pb = probs + b*L;
  const int t = threadIdx.x;
  float pv[8]; int bd[8];
  const int base = t*8;
  float psum=0.f; int cnt=0;
  #pragma unroll
  for (int j=0;j<8;j++) {
    pv[j] = pb[base+j];
    bd[j] = (base+j == 0) || (pv[j] > 0.5f);
    cnt += bd[j];
    psum += pv[j];
  }
  const int lane = t & 63, w = t >> 6;
  int x = cnt;
  #pragma unroll
  for (int off=1; off<64; off<<=1) {
    int y = __shfl_up(x, off);
    if (lane >= off) x += y;
  }
  float ps = psum;
  #pragma unroll
  for (int m=32;m>=1;m>>=1) ps += __shfl_xor(ps, m);
  __shared__ int wsum[16]; __shared__ int wpre[17]; __shared__ float fsum[16];
  if (lane == 63) wsum[w] = x;
  if (lane == 0)  fsum[w] = ps;
  __syncthreads();
  if (t == 0) {
    int run = 0; float tot = 0.f;
    for (int i=0;i<16;i++) { wpre[i] = run; run += wsum[i]; tot += fsum[i]; }
    wpre[16] = run;
    num_chunks[b] = run;
    float Gm = tot / (float)L;
    float Fm = (float)run / (float)L;
    auxvals[b] = 1.2f * (5.f*Fm*Gm + (1.f-Fm)*(1.f-Gm));
  }
  __syncthreads();
  int rank = wpre[w] + (x - cnt);
  #pragma unroll
  for (int j=0;j<8;j++) {
    if (bd[j]) { bpos[b*L + rank] = base + j; rank++; }
  }
}

// ---------------- K5A: per-segment scan -> down, hend, Pseg ----------------
__global__ __launch_bounds__(512) void k_scan_local(const float* __restrict__ tokens,
                                                    const float* __restrict__ probs,
                                                    const int* __restrict__ bpos,
                                                    const int* __restrict__ num_chunks,
                                                    float* __restrict__ hend,
                                                    float* __restrict__ Pseg,
                                                    float* __restrict__ down) {
  const int b = blockIdx.x / NSEG;
  const int s = blockIdx.x - b * NSEG;
  const int c = threadIdx.x;
  const int nc = num_chunks[b];
  const int i0 = s*SEGC;
  const int seg = b*NSEG + s;
  const int z0 = (i0 > nc) ? i0 : nc;
  for (int i = z0; i < i0 + SEGC; ++i)
    down[((size_t)(b*L + i))*512 + c] = 0.f;
  if (i0 >= nc) {
    hend[(size_t)seg*512 + c] = 0.f;
    if (c==0) Pseg[seg] = 1.f;
    return;
  }
  const int iend = (i0+SEGC < nc) ? i0+SEGC : nc;
  const int cntc = iend - i0;
  __shared__ float p_s[SEGC];
  __shared__ int n_s[SEGC];
  if (c < cntc) {
    int n = bpos[b*L + i0 + c];
    n_s[c] = n;
    p_s[c] = probs[b*L + n];
  }
  __syncthreads();
  float h = 0.f, gp = 1.f;
  for (int i = i0; i < iend; ++i) {
    const int ii = i - i0;
    const float p = p_s[ii];
    const float g = 1.f - p;
    const float x = tokens[((size_t)(b*L + n_s[ii]))*512 + c] * p;
    h = fmaf(g, h, x);
    gp *= g;
    down[((size_t)(b*L + i))*512 + c] = x;
  }
  hend[(size_t)seg*512 + c] = h;
  if (c==0) Pseg[seg] = gp;
}

// ---------------- K5B: parallel log-scan of segment carries (+ fused aux) ----------------
__global__ __launch_bounds__(512) void k_seg_scan(const float* __restrict__ hend,
                                                  const float* __restrict__ Pseg,
                                                  float* __restrict__ carry_in,
                                                  const float* __restrict__ auxvals,
                                                  float* __restrict__ outp) {
  if (blockIdx.x == 0 && threadIdx.x == 0)
    outp[0] = (auxvals[0]+auxvals[1]+auxvals[2]+auxvals[3]) * 0.25f * 0.03f;
  const int b   = blockIdx.x >> 7;
  const int gch = blockIdx.x & 127;
  const int sg  = threadIdx.x & 127;
  const int cl  = threadIdx.x >> 7;
  const int ch  = gch*4 + cl;
  const int seg = b*NSEG + sg;
  float h = hend[(size_t)seg*512 + ch];
  float P = Pseg[seg];
  __shared__ float sh[512], sP[512];
  const int idx = cl*128 + sg;
  #pragma unroll
  for (int off=1; off<NSEG; off<<=1) {
    sh[idx] = h; sP[idx] = P;
    __syncthreads();
    if (sg >= off) {
      h = fmaf(P, sh[idx-off], h);
      P = P * sP[idx-off];
    }
    __syncthreads();
  }
  sh[idx] = h;
  __syncthreads();
  carry_in[(size_t)seg*512 + ch] = (sg==0) ? 0.f : sh[idx-1];
}

// ---------------- K5C: replay scan (x from down) + expand to upsampled ----------------
__global__ __launch_bounds__(512) void k_expand(const float* __restrict__ down,
                                                const float* __restrict__ probs,
                                                const int* __restrict__ bpos,
                                                const int* __restrict__ num_chunks,
                                                const float* __restrict__ carry_in,
                                                float* __restrict__ up) {
  const int b = blockIdx.x / NSEG;
  const int s = blockIdx.x - b * NSEG;
  const int c = threadIdx.x;
  const int nc = num_chunks[b];
  const int i0 = s*SEGC;
  if (i0 >= nc) return;
  const int iend = (i0+SEGC < nc) ? i0+SEGC : nc;
  const int cntc = iend - i0;
  __shared__ float p_s[SEGC];
  __shared__ int n_s[SEGC+1];
  if (c < cntc) {
    int n = bpos[b*L + i0 + c];
    n_s[c] = n;
    p_s[c] = probs[b*L + n];
  }
  if (c == 0)   n_s[cntc] = (iend < nc) ? bpos[b*L + iend] : L;
  __syncthreads();
  float h = carry_in[((size_t)(b*NSEG + s))*512 + c];
  for (int i = i0; i < iend; ++i) {
    const int ii = i - i0;
    const float g = 1.f - p_s[ii];
    const float x = down[((size_t)(b*L + i))*512 + c];
    h = fmaf(g, h, x);
    const int n0 = n_s[ii], n1 = n_s[ii+1];
    for (int n = n0; n < n1; ++n)
      up[((size_t)(b*L + n))*512 + c] = h;
  }
}

extern "C" void kernel_launch(void* const* d_in, const int* in_sizes, int n_in,
                              void* d_out, int out_size, void* d_ws, size_t ws_size,
                              hipStream_t stream) {
  const float* tokens    = (const float*)d_in[0];
  const float* Wqk       = (const float*)d_in[1];
  const float* start_key = (const float*)d_in[2];
  float* out  = (float*)d_out;
  float* down = out;
  float* up   = out + (size_t)M_TOT*512;
  float* qk   = out;                           // fallback path only

  char* ws = (char*)d_ws;
  const size_t A_BYTES = (size_t)M_TOT*512*2;
  const size_t W_BYTES = (size_t)1024*512*2;
  const size_t STAGED_BASE = 3*A_BYTES + 3*W_BYTES;
  const size_t SMALL_BYTES = (size_t)M_TOT*4*2 + (size_t)BATCH*NSEG*512*4*2
                           + (size_t)BATCH*NSEG*4 + BATCH*4*2
                           + (size_t)M_TOT*4*3 + 256*4 + (size_t)256*512*4*2 + 1024;
  const bool staged = ws_size >= STAGED_BASE + SMALL_BYTES;

  unsigned short* A1 = (unsigned short*)ws;
  unsigned short* A2 = (unsigned short*)(ws + A_BYTES);
  unsigned short* A3 = (unsigned short*)(ws + 2*A_BYTES);
  unsigned short* W1 = (unsigned short*)(ws + 3*A_BYTES);
  unsigned short* W2 = (unsigned short*)(ws + 3*A_BYTES + W_BYTES);
  unsigned short* W3 = (unsigned short*)(ws + 3*A_BYTES + 2*W_BYTES);

  size_t off = staged ? STAGED_BASE : 0;
  float* probs    = (float*)(ws + off); off += (size_t)M_TOT*4;
  int*   bpos     = (int*)  (ws + off); off += (size_t)M_TOT*4;
  float* hend     = (float*)(ws + off); off += (size_t)BATCH*NSEG*512*4;
  float* carry_in = (float*)(ws + off); off += (size_t)BATCH*NSEG*512*4;
  float* Pseg     = (float*)(ws + off); off += (size_t)BATCH*NSEG*4;
  int*   num_chunks = (int*)(ws + off); off += (size_t)BATCH*4;
  float* auxvals  = (float*)(ws + off); off += (size_t)BATCH*4;
  float* dotv     = (float*)(ws + off); off += (size_t)M_TOT*4;   // also nq/nk below
  float* nqrow    = (float*)(ws + off); off += (size_t)M_TOT*4;
  float* nkrow    = (float*)(ws + off); off += (size_t)M_TOT*4;
  float* nkS      = (float*)(ws + off); off += 256*4;
  float* qstr     = (float*)(ws + off); off += (size_t)256*512*4;
  float* kstr     = (float*)(ws + off); off += (size_t)256*512*4;

  if (staged) {
    k_split<<<8448, 256, 0, stream>>>(tokens, Wqk, A1, A2, A3, W1, W2, W3);
    k_zero3<<<(3*M_TOT)/256, 256, 0, stream>>>(dotv);   // zeroes dotv+nqrow+nkrow (contiguous)
    k_gemm_fused<<<1024, 512, 0, stream>>>(A1, A2, A3, W1, W2, W3,
                                           dotv, nqrow, nkrow, qstr, kstr);
    k_straddle<<<64, 256, 0, stream>>>(qstr, kstr, start_key, nkrow, dotv, nkS);
    k_probs<<<M_TOT/256, 256, 0, stream>>>(dotv, nqrow, nkrow, nkS, probs);
  } else {
    k_gemm<<<2048, 256, 0, stream>>>(tokens, Wqk, qk);
    k_cos<<<M_TOT/4, 256, 0, stream>>>(qk, start_key, probs);
  }
  k_scan_bd<<<BATCH, 1024, 0, stream>>>(probs, bpos, num_chunks, auxvals);
  k_scan_local<<<BATCH*NSEG, 512, 0, stream>>>(tokens, probs, bpos, num_chunks,
                                               hend, Pseg, down);
  k_seg_scan<<<BATCH*NSEG, 512, 0, stream>>>(hend, Pseg, carry_in,
                                             auxvals, out + (size_t)2*M_TOT*512);
  k_expand<<<BATCH*NSEG, 512, 0, stream>>>(down, probs, bpos, num_chunks, carry_in, up);
}

// Round 7
// 341.495 us; speedup vs baseline: 1.7169x; 1.7169x over previous
//
#include <hip/hip_runtime.h>
#include <cstdint>
#include <cstddef>

#define L 8192
#define BATCH 4
#define DQK 512
#define M_TOT (BATCH*L)   // 32768 positions
#define NSEG 256          // segments per batch
#define SEGC 32           // chunks per segment
#define EPSC 1e-8f

typedef __attribute__((ext_vector_type(8))) short bf16x8;
typedef __attribute__((ext_vector_type(4))) float f32x4;
typedef __attribute__((ext_vector_type(8))) unsigned short u16x8;

// ---------- helpers ----------
__device__ __forceinline__ unsigned short bf16_rne(float x) {
  union { float f; unsigned u; } v; v.f = x;
  unsigned r = v.u + 0x7fffu + ((v.u >> 16) & 1u);
  return (unsigned short)(r >> 16);
}
__device__ __forceinline__ float bf16_tof(unsigned short b) {
  union { unsigned u; float f; } v; v.u = ((unsigned)b) << 16;
  return v.f;
}
__device__ __forceinline__ void gload_lds16(const void* g, void* l) {
  __builtin_amdgcn_global_load_lds(
      (const __attribute__((address_space(1))) unsigned int*)g,
      (__attribute__((address_space(3))) unsigned int*)l, 16, 0, 0);
}

// ---------------- K0: split f32 -> 3x bf16 ----------------
__global__ __launch_bounds__(256) void k_split(const float* __restrict__ tokens,
                                               const float* __restrict__ Wqk,
                                               unsigned short* __restrict__ A1,
                                               unsigned short* __restrict__ A2,
                                               unsigned short* __restrict__ A3,
                                               unsigned short* __restrict__ W1,
                                               unsigned short* __restrict__ W2,
                                               unsigned short* __restrict__ W3) {
  const float* src; unsigned short *d1, *d2, *d3; size_t e0;
  if (blockIdx.x < 8192) {
    src = tokens; d1 = A1; d2 = A2; d3 = A3;
    e0 = ((size_t)blockIdx.x * 256 + threadIdx.x) * 8;
  } else {
    src = Wqk; d1 = W1; d2 = W2; d3 = W3;
    e0 = ((size_t)(blockIdx.x - 8192) * 256 + threadIdx.x) * 8;
  }
  float v[8];
  *(float4*)&v[0] = *(const float4*)(src + e0);
  *(float4*)&v[4] = *(const float4*)(src + e0 + 4);
  unsigned short o1[8], o2[8], o3[8];
  #pragma unroll
  for (int j = 0; j < 8; ++j) {
    float x = v[j];
    unsigned short b1 = bf16_rne(x);
    float r1 = x - bf16_tof(b1);
    unsigned short b2 = bf16_rne(r1);
    float r2 = r1 - bf16_tof(b2);
    unsigned short b3 = bf16_rne(r2);
    o1[j] = b1; o2[j] = b2; o3[j] = b3;
  }
  *(u16x8*)(d1 + e0) = *(u16x8*)o1;
  *(u16x8*)(d2 + e0) = *(u16x8*)o2;
  *(u16x8*)(d3 + e0) = *(u16x8*)o3;
}

// ---------------- K1b: bf16x3 MFMA GEMM (16x16x32, R5-proven) ----------------
__global__ __launch_bounds__(256, 3) void k_gemm_bf16(
    const unsigned short* __restrict__ A1, const unsigned short* __restrict__ A2,
    const unsigned short* __restrict__ A3,
    const unsigned short* __restrict__ W1, const unsigned short* __restrict__ W2,
    const unsigned short* __restrict__ W3,
    float* __restrict__ C) {
  __shared__ unsigned short lds[6 * 512 * 8];  // 48KB
  // T1 XCD-chunked swizzle (nwg=2048 % 8 == 0, bijective)
  const int g = (blockIdx.x & 7) * 256 + (blockIdx.x >> 3);
  const int bx = g & 7;     // N-tile (1024/128)
  const int by = g >> 3;    // M-tile (32768/128)
  const int t = threadIdx.x;
  const int lane = t & 63;
  const int w = t >> 6;
  const int wr = w >> 1, wc = w & 1;

  f32x4 acc[4][4];
  #pragma unroll
  for (int i = 0; i < 4; ++i)
    #pragma unroll
    for (int j = 0; j < 4; ++j) acc[i][j] = (f32x4){0.f, 0.f, 0.f, 0.f};

  const unsigned short* srcA[3] = {A1, A2, A3};
  const unsigned short* srcW[3] = {W1, W2, W3};
  const int arow = by * 128;
  const int wrow = bx * 128;
  const int kg = lane >> 4;
  const int fr = lane & 15;

  for (int ks = 0; ks < 16; ++ks) {
    __syncthreads();
    const int kofs = ks * 32;
    #pragma unroll
    for (int s = 0; s < 3; ++s) {
      #pragma unroll
      for (int it = 0; it < 2; ++it) {
        const int p = it * 256 + t;
        const int row = p & 127, pg = p >> 7;
        gload_lds16(srcA[s] + (size_t)(arow + row) * 512 + kofs + pg * 8,
                    &lds[(s * 512 + p) * 8]);
        gload_lds16(srcW[s] + (size_t)(wrow + row) * 512 + kofs + pg * 8,
                    &lds[((3 + s) * 512 + p) * 8]);
      }
    }
    __syncthreads();

    bf16x8 bfr[4][3];
    #pragma unroll
    for (int nf = 0; nf < 4; ++nf) {
      const int row = wc * 64 + nf * 16 + fr;
      #pragma unroll
      for (int s = 0; s < 3; ++s)
        bfr[nf][s] = *(const bf16x8*)&lds[(((3 + s) * 512) + kg * 128 + row) * 8];
    }
    #pragma unroll
    for (int mf = 0; mf < 4; ++mf) {
      const int row = wr * 64 + mf * 16 + fr;
      bf16x8 a1 = *(const bf16x8*)&lds[((0 * 512) + kg * 128 + row) * 8];
      bf16x8 a2 = *(const bf16x8*)&lds[((1 * 512) + kg * 128 + row) * 8];
      bf16x8 a3 = *(const bf16x8*)&lds[((2 * 512) + kg * 128 + row) * 8];
      #pragma unroll
      for (int nf = 0; nf < 4; ++nf) {
        f32x4 c = acc[mf][nf];
        c = __builtin_amdgcn_mfma_f32_16x16x32_bf16(a1, bfr[nf][0], c, 0, 0, 0);
        c = __builtin_amdgcn_mfma_f32_16x16x32_bf16(a1, bfr[nf][1], c, 0, 0, 0);
        c = __builtin_amdgcn_mfma_f32_16x16x32_bf16(a2, bfr[nf][0], c, 0, 0, 0);
        c = __builtin_amdgcn_mfma_f32_16x16x32_bf16(a2, bfr[nf][1], c, 0, 0, 0);
        c = __builtin_amdgcn_mfma_f32_16x16x32_bf16(a1, bfr[nf][2], c, 0, 0, 0);
        c = __builtin_amdgcn_mfma_f32_16x16x32_bf16(a3, bfr[nf][0], c, 0, 0, 0);
        acc[mf][nf] = c;
      }
    }
  }
  const int fq = lane >> 4;
  #pragma unroll
  for (int mf = 0; mf < 4; ++mf) {
    #pragma unroll
    for (int nf = 0; nf < 4; ++nf) {
      const int col = bx * 128 + wc * 64 + nf * 16 + fr;
      #pragma unroll
      for (int r = 0; r < 4; ++r) {
        const int rrow = by * 128 + wr * 64 + mf * 16 + fq * 4 + r;
        C[(size_t)rrow * 1024 + col] = acc[mf][nf][r];
      }
    }
  }
}

// ---------------- K1: fallback f32 GEMM ----------------
__global__ __launch_bounds__(256) void k_gemm(const float* __restrict__ A,
                                              const float* __restrict__ W,
                                              float* __restrict__ C) {
  __shared__ float As[8][128];
  __shared__ float Bs[8][128];
  const int bx = blockIdx.x & 7;
  const int by = blockIdx.x >> 3;
  const int t  = threadIdx.x;
  const int tx = t & 15, ty = t >> 4;
  const int lr = t >> 1;
  const int lc = (t & 1) * 4;
  const float* Ag = A + (size_t)(by*128 + lr)*512 + lc;
  const float* Wg = W + (size_t)(bx*128 + lr)*512 + lc;
  float acc[8][8];
  #pragma unroll
  for (int i=0;i<8;i++)
    #pragma unroll
    for (int j=0;j<8;j++) acc[i][j]=0.f;

  for (int k0 = 0; k0 < 512; k0 += 8) {
    float4 av = *(const float4*)(Ag + k0);
    float4 bv = *(const float4*)(Wg + k0);
    __syncthreads();
    As[lc+0][lr]=av.x; As[lc+1][lr]=av.y; As[lc+2][lr]=av.z; As[lc+3][lr]=av.w;
    Bs[lc+0][lr]=bv.x; Bs[lc+1][lr]=bv.y; Bs[lc+2][lr]=bv.z; Bs[lc+3][lr]=bv.w;
    __syncthreads();
    #pragma unroll
    for (int kk=0;kk<8;kk++) {
      float af[8], bf[8];
      *(float4*)&af[0] = *(const float4*)&As[kk][ty*8];
      *(float4*)&af[4] = *(const float4*)&As[kk][ty*8+4];
      *(float4*)&bf[0] = *(const float4*)&Bs[kk][tx*8];
      *(float4*)&bf[4] = *(const float4*)&Bs[kk][tx*8+4];
      #pragma unroll
      for (int i=0;i<8;i++)
        #pragma unroll
        for (int j=0;j<8;j++)
          acc[i][j] = fmaf(af[i], bf[j], acc[i][j]);
    }
  }
  const int crow = by*128 + ty*8;
  const int ccol = bx*128 + tx*8;
  #pragma unroll
  for (int i=0;i<8;i++) {
    float* cp = C + (size_t)(crow+i)*1024 + ccol;
    *(float4*)cp     = make_float4(acc[i][0],acc[i][1],acc[i][2],acc[i][3]);
    *(float4*)(cp+4) = make_float4(acc[i][4],acc[i][5],acc[i][6],acc[i][7]);
  }
}

// ---------------- K2: cosine -> probs ----------------
__global__ __launch_bounds__(256) void k_cos(const float* __restrict__ qk,
                                             const float* __restrict__ start_key,
                                             float* __restrict__ probs) {
  const int wid = threadIdx.x >> 6;
  const int lane = threadIdx.x & 63;
  const int p = blockIdx.x*4 + wid;
  const int n = p & (L-1);
  const float* q  = qk + (size_t)p*1024;
  const float* ks = (n==0) ? start_key : (qk + (size_t)(p-1)*1024 + 512);
  float dot=0.f, nq=0.f, nk=0.f;
  const int e0 = lane*8;
  #pragma unroll
  for (int j=0;j<8;j+=4) {
    float4 qv = *(const float4*)(q+e0+j);
    float4 kv = *(const float4*)(ks+e0+j);
    dot = fmaf(qv.x,kv.x,dot); dot = fmaf(qv.y,kv.y,dot);
    dot = fmaf(qv.z,kv.z,dot); dot = fmaf(qv.w,kv.w,dot);
    nq  = fmaf(qv.x,qv.x,nq);  nq  = fmaf(qv.y,qv.y,nq);
    nq  = fmaf(qv.z,qv.z,nq);  nq  = fmaf(qv.w,qv.w,nq);
    nk  = fmaf(kv.x,kv.x,nk);  nk  = fmaf(kv.y,kv.y,nk);
    nk  = fmaf(kv.z,kv.z,nk);  nk  = fmaf(kv.w,kv.w,nk);
  }
  #pragma unroll
  for (int m=32;m>=1;m>>=1) {
    dot += __shfl_xor(dot,m);
    nq  += __shfl_xor(nq,m);
    nk  += __shfl_xor(nk,m);
  }
  if (lane==0) {
    float na = fmaxf(sqrtf(nq), EPSC);
    float nb = fmaxf(sqrtf(nk), EPSC);
    float c  = dot/(na*nb);
    probs[p] = 0.5f*(1.f - c);
  }
}

// ---------------- K3: per-batch boundary prefix-scan, bpos, aux ----------------
__global__ __launch_bounds__(1024) void k_scan_bd(const float* __restrict__ probs,
                                                  int* __restrict__ bpos,
                                                  int* __restrict__ num_chunks,
                                                  float* __restrict__ auxvals) {
  const int b = blockIdx.x;
  const float* pb = probs + b*L;
  const int t = threadIdx.x;
  float pv[8]; int bd[8];
  const int base = t*8;
  float psum=0.f; int cnt=0;
  #pragma unroll
  for (int j=0;j<8;j++) {
    pv[j] = pb[base+j];
    bd[j] = (base+j == 0) || (pv[j] > 0.5f);
    cnt += bd[j];
    psum += pv[j];
  }
  const int lane = t & 63, w = t >> 6;
  int x = cnt;
  #pragma unroll
  for (int off=1; off<64; off<<=1) {
    int y = __shfl_up(x, off);
    if (lane >= off) x += y;
  }
  float ps = psum;
  #pragma unroll
  for (int m=32;m>=1;m>>=1) ps += __shfl_xor(ps, m);
  __shared__ int wsum[16]; __shared__ int wpre[17]; __shared__ float fsum[16];
  if (lane == 63) wsum[w] = x;
  if (lane == 0)  fsum[w] = ps;
  __syncthreads();
  if (t == 0) {
    int run = 0; float tot = 0.f;
    for (int i=0;i<16;i++) { wpre[i] = run; run += wsum[i]; tot += fsum[i]; }
    wpre[16] = run;
    num_chunks[b] = run;
    float Gm = tot / (float)L;
    float Fm = (float)run / (float)L;
    auxvals[b] = 1.2f * (5.f*Fm*Gm + (1.f-Fm)*(1.f-Gm));
  }
  __syncthreads();
  int rank = wpre[w] + (x - cnt);
  #pragma unroll
  for (int j=0;j<8;j++) {
    if (bd[j]) { bpos[b*L + rank] = base + j; rank++; }
  }
}

// ---------------- K5A: per-segment scan -> down, hend, Pseg ----------------
__global__ __launch_bounds__(512) void k_scan_local(const float* __restrict__ tokens,
                                                    const float* __restrict__ probs,
                                                    const int* __restrict__ bpos,
                                                    const int* __restrict__ num_chunks,
                                                    float* __restrict__ hend,
                                                    float* __restrict__ Pseg,
                                                    float* __restrict__ down) {
  const int b = blockIdx.x / NSEG;
  const int s = blockIdx.x - b * NSEG;
  const int c = threadIdx.x;
  const int nc = num_chunks[b];
  const int i0 = s*SEGC;
  const int seg = b*NSEG + s;
  const int z0 = (i0 > nc) ? i0 : nc;
  for (int i = z0; i < i0 + SEGC; ++i)
    down[((size_t)(b*L + i))*512 + c] = 0.f;
  if (i0 >= nc) {
    hend[(size_t)seg*512 + c] = 0.f;
    if (c==0) Pseg[seg] = 1.f;
    return;
  }
  const int iend = (i0+SEGC < nc) ? i0+SEGC : nc;
  const int cntc = iend - i0;
  __shared__ float p_s[SEGC];
  __shared__ int n_s[SEGC];
  if (c < cntc) {
    int n = bpos[b*L + i0 + c];
    n_s[c] = n;
    p_s[c] = probs[b*L + n];
  }
  __syncthreads();
  float h = 0.f, gp = 1.f;
  for (int i = i0; i < iend; ++i) {
    const int ii = i - i0;
    const float p = p_s[ii];
    const float g = 1.f - p;
    const float x = tokens[((size_t)(b*L + n_s[ii]))*512 + c] * p;
    h = fmaf(g, h, x);
    gp *= g;
    down[((size_t)(b*L + i))*512 + c] = x;
  }
  hend[(size_t)seg*512 + c] = h;
  if (c==0) Pseg[seg] = gp;
}

// ------- K5B: parallel log-scan of 256 segment carries (+ fused aux output) -------
__global__ __launch_bounds__(512) void k_seg_scan(const float* __restrict__ hend,
                                                  const float* __restrict__ Pseg,
                                                  float* __restrict__ carry_in,
                                                  const float* __restrict__ auxvals,
                                                  float* __restrict__ outp) {
  if (blockIdx.x == 0 && threadIdx.x == 0)
    outp[0] = (auxvals[0]+auxvals[1]+auxvals[2]+auxvals[3]) * 0.25f * 0.03f;
  const int b   = blockIdx.x >> 8;       // batch (256 blocks per batch)
  const int gch = blockIdx.x & 255;      // channel group (2 ch each)
  const int sg  = threadIdx.x & 255;     // segment 0..255
  const int cl  = threadIdx.x >> 8;      // 0..1
  const int ch  = gch*2 + cl;
  const int seg = b*NSEG + sg;
  float h = hend[(size_t)seg*512 + ch];
  float P = Pseg[seg];
  __shared__ float sh[512], sP[512];
  const int idx = cl*256 + sg;
  #pragma unroll
  for (int off=1; off<NSEG; off<<=1) {
    sh[idx] = h; sP[idx] = P;
    __syncthreads();
    if (sg >= off) {
      h = fmaf(P, sh[idx-off], h);
      P = P * sP[idx-off];
    }
    __syncthreads();
  }
  sh[idx] = h;
  __syncthreads();
  carry_in[(size_t)seg*512 + ch] = (sg==0) ? 0.f : sh[idx-1];
}

// ---------------- K5C: replay scan (x from down) + expand to upsampled ----------------
__global__ __launch_bounds__(512) void k_expand(const float* __restrict__ down,
                                                const float* __restrict__ probs,
                                                const int* __restrict__ bpos,
                                                const int* __restrict__ num_chunks,
                                                const float* __restrict__ carry_in,
                                                float* __restrict__ up) {
  const int b = blockIdx.x / NSEG;
  const int s = blockIdx.x - b * NSEG;
  const int c = threadIdx.x;
  const int nc = num_chunks[b];
  const int i0 = s*SEGC;
  if (i0 >= nc) return;
  const int iend = (i0+SEGC < nc) ? i0+SEGC : nc;
  const int cntc = iend - i0;
  __shared__ float p_s[SEGC];
  __shared__ int n_s[SEGC+1];
  if (c < cntc) {
    int n = bpos[b*L + i0 + c];
    n_s[c] = n;
    p_s[c] = probs[b*L + n];
  }
  if (c == 0)   n_s[cntc] = (iend < nc) ? bpos[b*L + iend] : L;
  __syncthreads();
  float h = carry_in[((size_t)(b*NSEG + s))*512 + c];
  for (int i = i0; i < iend; ++i) {
    const int ii = i - i0;
    const float g = 1.f - p_s[ii];
    const float x = down[((size_t)(b*L + i))*512 + c];
    h = fmaf(g, h, x);
    const int n0 = n_s[ii], n1 = n_s[ii+1];
    for (int n = n0; n < n1; ++n)
      up[((size_t)(b*L + n))*512 + c] = h;
  }
}

extern "C" void kernel_launch(void* const* d_in, const int* in_sizes, int n_in,
                              void* d_out, int out_size, void* d_ws, size_t ws_size,
                              hipStream_t stream) {
  const float* tokens    = (const float*)d_in[0];
  const float* Wqk       = (const float*)d_in[1];
  const float* start_key = (const float*)d_in[2];
  float* out  = (float*)d_out;
  float* down = out;
  float* up   = out + (size_t)M_TOT*512;
  float* qk   = out;                           // stage qk[32768][1024] in output buffer

  char* ws = (char*)d_ws;
  const size_t A_BYTES = (size_t)M_TOT*512*2;       // 32 MiB per split
  const size_t W_BYTES = (size_t)1024*512*2;        // 1 MiB per split
  const size_t STAGED_BASE = 3*A_BYTES + 3*W_BYTES; // ~99 MiB
  const bool staged = ws_size >= STAGED_BASE + 4096;

  unsigned short* A1 = (unsigned short*)ws;
  unsigned short* A2 = (unsigned short*)(ws + A_BYTES);
  unsigned short* A3 = (unsigned short*)(ws + 2*A_BYTES);
  unsigned short* W1 = (unsigned short*)(ws + 3*A_BYTES);
  unsigned short* W2 = (unsigned short*)(ws + 3*A_BYTES + W_BYTES);
  unsigned short* W3 = (unsigned short*)(ws + 3*A_BYTES + 2*W_BYTES);

  // post-GEMM arrays alias the A-split region (dead after k_gemm_bf16):
  // probs is first written by k_cos, which runs after the GEMM has consumed A1..A3.
  size_t off = 0;
  float* probs    = (float*)(ws + off); off += (size_t)M_TOT*4;          // 128 KB
  int*   bpos     = (int*)  (ws + off); off += (size_t)M_TOT*4;          // 128 KB
  float* hend     = (float*)(ws + off); off += (size_t)BATCH*NSEG*512*4; // 2 MB
  float* carry_in = (float*)(ws + off); off += (size_t)BATCH*NSEG*512*4; // 2 MB
  float* Pseg     = (float*)(ws + off); off += (size_t)BATCH*NSEG*4;
  int*   num_chunks = (int*)(ws + off); off += (size_t)BATCH*4;
  float* auxvals  = (float*)(ws + off); off += (size_t)BATCH*4;

  if (staged) {
    k_split<<<8448, 256, 0, stream>>>(tokens, Wqk, A1, A2, A3, W1, W2, W3);
    k_gemm_bf16<<<2048, 256, 0, stream>>>(A1, A2, A3, W1, W2, W3, qk);
  } else {
    k_gemm<<<2048, 256, 0, stream>>>(tokens, Wqk, qk);
  }
  k_cos<<<M_TOT/4, 256, 0, stream>>>(qk, start_key, probs);
  k_scan_bd<<<BATCH, 1024, 0, stream>>>(probs, bpos, num_chunks, auxvals);
  k_scan_local<<<BATCH*NSEG, 512, 0, stream>>>(tokens, probs, bpos, num_chunks,
                                               hend, Pseg, down);
  k_seg_scan<<<BATCH*NSEG, 512, 0, stream>>>(hend, Pseg, carry_in,
                                             auxvals, out + (size_t)2*M_TOT*512);
  k_expand<<<BATCH*NSEG, 512, 0, stream>>>(down, probs, bpos, num_chunks, carry_in, up);
}